// Round 2
// 3189.342 us; speedup vs baseline: 3.4699x; 3.4699x over previous
//
#include <hip/hip_runtime.h>
#include <math.h>

// Problem constants
#define BT_ROWS 4096
#define HS 2048
#define HT 4096
#define NV 32000
#define IGNORE_IDX (-100)

// Tiling
#define BM 64          // rows per block
#define BN 320         // vocab cols per block (chunk)
#define BK 32          // k-step
#define NCHUNK 100     // 32000 / 320
#define NRT 64         // 4096 / 64 row tiles
#define CTW 5          // (old path) col 16-tiles per wave
#define RT 4           // (old path) row 16-tiles per wave

// New-path K-step counts
#define NSTEPS_S (HS / BK)            // 64
#define NSTEPS_T (HT / BK)            // 128
#define NSTEPS   (NSTEPS_S + NSTEPS_T)

using bf16x8 = __attribute__((ext_vector_type(8))) short;
using f32x4  = __attribute__((ext_vector_type(4))) float;

__device__ __forceinline__ unsigned short f2bf(float f) {
    union { float f; unsigned u; } v; v.f = f;
    unsigned r = v.u + 0x7fffu + ((v.u >> 16) & 1u);
    return (unsigned short)(r >> 16);
}

__device__ __forceinline__ void gload16(const void* g, void* l) {
    __builtin_amdgcn_global_load_lds(
        (const __attribute__((address_space(1))) unsigned*)g,
        (__attribute__((address_space(3))) unsigned*)l, 16, 0, 0);
}

// ---------------- fp32 -> bf16 convert (one-time) ----------------
__global__ void convert_kernel(const float* __restrict__ in,
                               uint4* __restrict__ out, long n8) {
    long i = (long)blockIdx.x * blockDim.x + threadIdx.x;
    const long stride = (long)gridDim.x * blockDim.x;
    const float4* in4 = (const float4*)in;
    for (; i < n8; i += stride) {
        const float4 a = in4[i * 2];
        const float4 b = in4[i * 2 + 1];
        uint4 o;
        o.x = (unsigned)f2bf(a.x) | ((unsigned)f2bf(a.y) << 16);
        o.y = (unsigned)f2bf(a.z) | ((unsigned)f2bf(a.w) << 16);
        o.z = (unsigned)f2bf(b.x) | ((unsigned)f2bf(b.y) << 16);
        o.w = (unsigned)f2bf(b.z) | ((unsigned)f2bf(b.w) << 16);
        out[i] = o;
    }
}

// ---------------- new GEMM-partials kernel ----------------
// 512 threads = 8 waves in a 2x4 grid. Wave (wr,wc) owns rows wr*32..+31,
// cols wc*80..+79 of the 64x320 tile. Dual accumulators (student+teacher)
// = 2*(2*5) f32x4 = 80 VGPRs. Staging: 24KB/step via global_load_lds
// (3 x 16B instrs per wave), double-buffered, 1 barrier per K-step.
__global__ __launch_bounds__(512, 4)
void partial2_kernel(const unsigned short* __restrict__ sA,
                     const unsigned short* __restrict__ tA,
                     const unsigned short* __restrict__ sW,
                     const unsigned short* __restrict__ tW,
                     const int*   __restrict__ target,
                     float* __restrict__ partials) {
    __shared__ alignas(16) union {
        unsigned short stage[2][12288];                    // 2 x 24KB
        struct { float red[4][BM][5]; float tgt[BM]; } ep; // epilogue scratch
    } sm;

    const int tid  = threadIdx.x;
    const int lane = tid & 63;
    const int w    = tid >> 6;        // 0..7
    const int wr   = w >> 2;          // 0..1 (row half)
    const int wc   = w & 3;           // 0..3 (col quarter)
    const int c16  = lane & 15;
    const int q    = lane >> 4;

    const int rBase = blockIdx.x * BM;
    const int cIdx  = blockIdx.y;
    const int vBase = cIdx * BN;

    // Per-lane global source base addrs for the 3 staging instrs.
    // Linear stage layout: A[64][32]bf16 (4KB) ++ B[320][32]bf16 (20KB).
    // LDS byte o = w*3072 + i*1024 + lane*16 maps to (tensor,row,kbyte).
    const char* pS[3]; const char* pT[3];
    #pragma unroll
    for (int i = 0; i < 3; ++i) {
        const int o = w * 3072 + i * 1024 + lane * 16;
        if (o < 4096) {
            const int r = o >> 6, kb = o & 63;
            pS[i] = (const char*)sA + (size_t)(rBase + r) * (HS * 2) + kb;
            pT[i] = (const char*)tA + (size_t)(rBase + r) * (HT * 2) + kb;
        } else {
            const int r = (o - 4096) >> 6, kb = o & 63;
            pS[i] = (const char*)sW + (size_t)(vBase + r) * (HS * 2) + kb;
            pT[i] = (const char*)tW + (size_t)(vBase + r) * (HT * 2) + kb;
        }
    }

    // LDS read offsets (ushort units).
    int aOff[2], bOff[5];
    #pragma unroll
    for (int rt = 0; rt < 2; ++rt) aOff[rt] = (wr * 32 + rt * 16 + c16) * 32 + q * 8;
    #pragma unroll
    for (int ct = 0; ct < 5; ++ct) bOff[ct] = 2048 + (wc * 80 + ct * 16 + c16) * 32 + q * 8;

    f32x4 accS[2][5], accT[2][5];
    const f32x4 zero = {0.f, 0.f, 0.f, 0.f};
    #pragma unroll
    for (int a = 0; a < 2; a++)
        #pragma unroll
        for (int b = 0; b < 5; b++) { accS[a][b] = zero; accT[a][b] = zero; }

    auto stage = [&](int s, int par) {
        if (s >= NSTEPS) return;
        unsigned short* dst = &sm.stage[par][w * 1536];
        if (s < NSTEPS_S) {
            const size_t ko = (size_t)s * 64;
            #pragma unroll
            for (int i = 0; i < 3; ++i) gload16(pS[i] + ko, dst + i * 512);
        } else {
            const size_t ko = (size_t)(s - NSTEPS_S) * 64;
            #pragma unroll
            for (int i = 0; i < 3; ++i) gload16(pT[i] + ko, dst + i * 512);
        }
    };

    auto compute = [&](int par, f32x4 (&acc)[2][5]) {
        const unsigned short* buf = sm.stage[par];
        bf16x8 af[2];
        #pragma unroll
        for (int rt = 0; rt < 2; ++rt) af[rt] = *(const bf16x8*)(buf + aOff[rt]);
        #pragma unroll
        for (int ct = 0; ct < 5; ++ct) {
            const bf16x8 bv = *(const bf16x8*)(buf + bOff[ct]);
            #pragma unroll
            for (int rt = 0; rt < 2; ++rt)
                acc[rt][ct] = __builtin_amdgcn_mfma_f32_16x16x32_bf16(
                    af[rt], bv, acc[rt][ct], 0, 0, 0);
        }
    };

    stage(0, 0);
    __syncthreads();                  // compiler drains vmcnt(0) before barrier

    #pragma unroll 1
    for (int s = 0; s < NSTEPS_S; s += 2) {
        stage(s + 1, 1); compute(0, accS); __syncthreads();
        stage(s + 2, 0); compute(1, accS); __syncthreads();
    }
    #pragma unroll 1
    for (int s = NSTEPS_S; s < NSTEPS; s += 2) {
        stage(s + 1, 1); compute(0, accT); __syncthreads();
        stage(s + 2, 0); compute(1, accT); __syncthreads();
    }

    // ---- epilogue: per-row chunk stats (stage buffers dead -> union reuse) ----
    if (tid < BM) sm.ep.tgt[tid] = 0.0f;
    __syncthreads();

    #pragma unroll
    for (int rt = 0; rt < 2; rt++) {
        #pragma unroll
        for (int r = 0; r < 4; r++) {
            const int rowLocal = wr * 32 + rt * 16 + q * 4 + r;
            float sv[5], tv[5];
            #pragma unroll
            for (int ct = 0; ct < 5; ct++) { sv[ct] = accS[rt][ct][r]; tv[ct] = accT[rt][ct][r]; }

            const int tg = target[rBase + rowLocal];
            #pragma unroll
            for (int ct = 0; ct < 5; ct++)
                if (vBase + wc * 80 + ct * 16 + c16 == tg) sm.ep.tgt[rowLocal] = sv[ct];

            float mloc = sv[0], s2 = 0.f, t2 = 0.f, dot = 0.f;
            #pragma unroll
            for (int ct = 0; ct < 5; ct++) {
                mloc = fmaxf(mloc, sv[ct]);
                s2  += sv[ct] * sv[ct];
                t2  += tv[ct] * tv[ct];
                dot += sv[ct] * tv[ct];
            }
            #pragma unroll
            for (int mask = 1; mask < 16; mask <<= 1)
                mloc = fmaxf(mloc, __shfl_xor(mloc, mask, 64));
            float es = 0.f;
            #pragma unroll
            for (int ct = 0; ct < 5; ct++) es += expf(sv[ct] - mloc);
            #pragma unroll
            for (int mask = 1; mask < 16; mask <<= 1) {
                es  += __shfl_xor(es,  mask, 64);
                s2  += __shfl_xor(s2,  mask, 64);
                t2  += __shfl_xor(t2,  mask, 64);
                dot += __shfl_xor(dot, mask, 64);
            }
            if (c16 == 0) {
                sm.ep.red[wc][rowLocal][0] = mloc;
                sm.ep.red[wc][rowLocal][1] = es;
                sm.ep.red[wc][rowLocal][2] = dot;
                sm.ep.red[wc][rowLocal][3] = s2;
                sm.ep.red[wc][rowLocal][4] = t2;
            }
        }
    }
    __syncthreads();

    if (tid < BM) {
        float gm = -INFINITY, gl = 0.f, gd = 0.f, gs2 = 0.f, gt2 = 0.f;
        #pragma unroll
        for (int ww = 0; ww < 4; ww++) {
            float m = sm.ep.red[ww][tid][0], e = sm.ep.red[ww][tid][1];
            float nm = fmaxf(gm, m);
            gl = gl * expf(gm - nm) + e * expf(m - nm);
            gm = nm;
            gd  += sm.ep.red[ww][tid][2];
            gs2 += sm.ep.red[ww][tid][3];
            gt2 += sm.ep.red[ww][tid][4];
        }
        float* o = partials + ((size_t)cIdx * BT_ROWS + rBase + tid) * 6;
        o[0] = gm; o[1] = gl; o[2] = gd; o[3] = gs2; o[4] = gt2; o[5] = sm.ep.tgt[tid];
    }
}

// ---------------- old (proven) kernel — fallback if ws too small ----------------
__global__ void partial_kernel(const float* __restrict__ s_in,
                               const float* __restrict__ t_in,
                               const float* __restrict__ s_w,
                               const float* __restrict__ t_w,
                               const int*   __restrict__ target,
                               float* __restrict__ ws) {
    __shared__ alignas(16) unsigned short lA[BM][BK];
    __shared__ alignas(16) unsigned short lB[BN][BK];
    __shared__ float red[4][BM][5];
    __shared__ float tgtLogit[BM];

    const int tid   = threadIdx.x;
    const int rBase = blockIdx.x * BM;
    const int cIdx  = blockIdx.y;
    const int vBase = cIdx * BN;

    const int lane = tid & 63;
    const int w    = tid >> 6;
    const int c16  = lane & 15;
    const int q    = lane >> 4;
    const int wcol = w * (CTW * 16);

    if (tid < BM) tgtLogit[tid] = 0.0f;

    f32x4 accS[RT][CTW];
    f32x4 accT[RT][CTW];
    const f32x4 zero = {0.f, 0.f, 0.f, 0.f};
    #pragma unroll
    for (int a = 0; a < RT; a++)
        #pragma unroll
        for (int b = 0; b < CTW; b++) { accS[a][b] = zero; accT[a][b] = zero; }

    const int r0 = tid >> 3;
    const int cc = (tid & 7) * 4;

    auto run_gemm = [&](const float* __restrict__ X, const float* __restrict__ W,
                        int K, f32x4 (&acc)[RT][CTW]) {
        for (int kk = 0; kk < K; kk += BK) {
            __syncthreads();
            #pragma unroll
            for (int p = 0; p < 2; p++) {
                int row = r0 + p * 32;
                const float4 v = *(const float4*)&X[(size_t)(rBase + row) * K + kk + cc];
                ushort4 b;
                b.x = f2bf(v.x); b.y = f2bf(v.y); b.z = f2bf(v.z); b.w = f2bf(v.w);
                *(ushort4*)&lA[row][cc] = b;
            }
            #pragma unroll
            for (int p = 0; p < 10; p++) {
                int row = r0 + p * 32;
                const float4 v = *(const float4*)&W[(size_t)(vBase + row) * K + kk + cc];
                ushort4 b;
                b.x = f2bf(v.x); b.y = f2bf(v.y); b.z = f2bf(v.z); b.w = f2bf(v.w);
                *(ushort4*)&lB[row][cc] = b;
            }
            __syncthreads();

            bf16x8 af[RT];
            #pragma unroll
            for (int rt = 0; rt < RT; rt++)
                af[rt] = *(const bf16x8*)&lA[rt * 16 + c16][q * 8];
            #pragma unroll
            for (int ct = 0; ct < CTW; ct++) {
                bf16x8 bf = *(const bf16x8*)&lB[wcol + ct * 16 + c16][q * 8];
                #pragma unroll
                for (int rt = 0; rt < RT; rt++)
                    acc[rt][ct] = __builtin_amdgcn_mfma_f32_16x16x32_bf16(
                        af[rt], bf, acc[rt][ct], 0, 0, 0);
            }
        }
    };

    run_gemm(s_in, s_w, HS, accS);
    run_gemm(t_in, t_w, HT, accT);

    #pragma unroll
    for (int rt = 0; rt < RT; rt++) {
        #pragma unroll
        for (int r = 0; r < 4; r++) {
            const int rowLocal = rt * 16 + q * 4 + r;
            float sv[CTW], tv[CTW];
            #pragma unroll
            for (int ct = 0; ct < CTW; ct++) { sv[ct] = accS[rt][ct][r]; tv[ct] = accT[rt][ct][r]; }

            const int tg = target[rBase + rowLocal];
            #pragma unroll
            for (int ct = 0; ct < CTW; ct++)
                if (vBase + wcol + ct * 16 + c16 == tg) tgtLogit[rowLocal] = sv[ct];

            float mloc = sv[0], s2 = 0.f, t2 = 0.f, dot = 0.f;
            #pragma unroll
            for (int ct = 0; ct < CTW; ct++) {
                mloc = fmaxf(mloc, sv[ct]);
                s2 += sv[ct] * sv[ct];
                t2 += tv[ct] * tv[ct];
                dot += sv[ct] * tv[ct];
            }
            #pragma unroll
            for (int mask = 1; mask < 16; mask <<= 1)
                mloc = fmaxf(mloc, __shfl_xor(mloc, mask, 64));
            float es = 0.f;
            #pragma unroll
            for (int ct = 0; ct < CTW; ct++) es += expf(sv[ct] - mloc);
            #pragma unroll
            for (int mask = 1; mask < 16; mask <<= 1) {
                es  += __shfl_xor(es,  mask, 64);
                s2  += __shfl_xor(s2,  mask, 64);
                t2  += __shfl_xor(t2,  mask, 64);
                dot += __shfl_xor(dot, mask, 64);
            }
            if (c16 == 0) {
                red[w][rowLocal][0] = mloc;
                red[w][rowLocal][1] = es;
                red[w][rowLocal][2] = dot;
                red[w][rowLocal][3] = s2;
                red[w][rowLocal][4] = t2;
            }
        }
    }
    __syncthreads();

    if (tid < BM) {
        float gm = -INFINITY, gl = 0.f, gd = 0.f, gs2 = 0.f, gt2 = 0.f;
        #pragma unroll
        for (int ww = 0; ww < 4; ww++) {
            float m = red[ww][tid][0], e = red[ww][tid][1];
            float nm = fmaxf(gm, m);
            gl = gl * expf(gm - nm) + e * expf(m - nm);
            gm = nm;
            gd  += red[ww][tid][2];
            gs2 += red[ww][tid][3];
            gt2 += red[ww][tid][4];
        }
        float* o = ws + ((size_t)cIdx * BT_ROWS + rBase + tid) * 6;
        o[0] = gm; o[1] = gl; o[2] = gd; o[3] = gs2; o[4] = gt2; o[5] = tgtLogit[tid];
    }
}

__global__ void finalize_kernel(const float* __restrict__ ws,
                                const int* __restrict__ target,
                                float* __restrict__ out) {
    const int row = blockIdx.x * 256 + threadIdx.x;
    float gm = -INFINITY, gl = 0.f, gd = 0.f, gs2 = 0.f, gt2 = 0.f, gtg = 0.f;
    for (int c = 0; c < NCHUNK; c++) {
        const float* p = ws + ((size_t)c * BT_ROWS + row) * 6;
        float m = p[0], e = p[1];
        float nm = fmaxf(gm, m);
        gl = gl * expf(gm - nm) + e * expf(m - nm);
        gm = nm;
        gd += p[2]; gs2 += p[3]; gt2 += p[4]; gtg += p[5];
    }
    float logZ = gm + logf(gl);
    int tg = target[row];
    float hard = (tg != IGNORE_IDX) ? (logZ - gtg) : 0.f;
    float cosv = gd * rsqrtf(fmaxf(gs2, 1e-24f)) * rsqrtf(fmaxf(gt2, 1e-24f));
    float contrib = (0.5f * hard + 0.25f * (1.f - cosv)) * (1.f / (float)BT_ROWS);

    __shared__ float sred[256];
    sred[threadIdx.x] = contrib;
    __syncthreads();
    for (int s = 128; s > 0; s >>= 1) {
        if (threadIdx.x < s) sred[threadIdx.x] += sred[threadIdx.x + s];
        __syncthreads();
    }
    if (threadIdx.x == 0) atomicAdd(out, sred[0]);
}

extern "C" void kernel_launch(void* const* d_in, const int* in_sizes, int n_in,
                              void* d_out, int out_size, void* d_ws, size_t ws_size,
                              hipStream_t stream) {
    const float* s_in = (const float*)d_in[0];
    const float* t_in = (const float*)d_in[1];
    const float* s_w  = (const float*)d_in[2];
    const float* t_w  = (const float*)d_in[3];
    const int*   tgt  = (const int*)d_in[4];
    float* out = (float*)d_out;
    float* ws  = (float*)d_ws;

    hipMemsetAsync(d_out, 0, sizeof(float), stream);

    // bf16 workspace layout (bytes):
    //   sA: 0          .. 16,777,216      (4096x2048)
    //   tA: 16,777,216 .. 50,331,648      (4096x4096)
    //   sW: 50,331,648 .. 181,403,648     (32000x2048)
    //   tW: 181,403,648 .. 443,547,648    (32000x4096)
    //   partials: 443,547,648 + 100*4096*6*4 = 9,830,400
    const size_t NEED = 443547648ull + (size_t)NCHUNK * BT_ROWS * 6 * 4;

    if (ws_size >= NEED) {
        char* w0 = (char*)d_ws;
        unsigned short* sA = (unsigned short*)(w0);
        unsigned short* tA = (unsigned short*)(w0 + 16777216ull);
        unsigned short* sW = (unsigned short*)(w0 + 50331648ull);
        unsigned short* tW = (unsigned short*)(w0 + 181403648ull);
        float* partials    = (float*)(w0 + 443547648ull);

        convert_kernel<<<2048, 256, 0, stream>>>(s_in, (uint4*)sA, 1048576L);
        convert_kernel<<<2048, 256, 0, stream>>>(t_in, (uint4*)tA, 2097152L);
        convert_kernel<<<2048, 256, 0, stream>>>(s_w,  (uint4*)sW, 8192000L);
        convert_kernel<<<2048, 256, 0, stream>>>(t_w,  (uint4*)tW, 16384000L);

        partial2_kernel<<<dim3(NRT, NCHUNK), 512, 0, stream>>>(sA, tA, sW, tW, tgt, partials);
        finalize_kernel<<<BT_ROWS / 256, 256, 0, stream>>>(partials, tgt, out);
    } else {
        // fallback: previous proven path (register-staged fp32->bf16)
        partial_kernel<<<dim3(NRT, NCHUNK), 256, 0, stream>>>(s_in, t_in, s_w, t_w, tgt, ws);
        finalize_kernel<<<BT_ROWS / 256, 256, 0, stream>>>(ws, tgt, out);
    }
}